// Round 1
// baseline (246.356 us; speedup 1.0000x reference)
//
#include <hip/hip_runtime.h>

#define BB 8
#define NN 2048
#define DD 1024
#define GG 8
#define CAP 320
#define NTOK (BB * NN)
#define EPSV 1e-9f
#define THRESH 0.2f

// ---------------------------------------------------------------------------
// Kernel 1: logits GEMV + softmax + top2 + normalize + threshold.
// One wave handles 4 tokens. W staged transposed in LDS: Wt[e][k], read as
// float4 with consecutive-lane addresses (conflict-free b128 pattern).
// Record per token: {int e1, float g1n, int e2_or_-1, float g2n}.
// ---------------------------------------------------------------------------
__global__ __launch_bounds__(256) void gate_kernel(const float* __restrict__ x,
                                                   const float* __restrict__ W,
                                                   float4* __restrict__ rec) {
    __shared__ float Wt[GG * DD];
    const float4* W4 = (const float4*)W;
    for (int r = threadIdx.x; r < DD; r += 256) {
        float4 a = W4[r * 2];
        float4 b = W4[r * 2 + 1];
        Wt[0 * DD + r] = a.x; Wt[1 * DD + r] = a.y;
        Wt[2 * DD + r] = a.z; Wt[3 * DD + r] = a.w;
        Wt[4 * DD + r] = b.x; Wt[5 * DD + r] = b.y;
        Wt[6 * DD + r] = b.z; Wt[7 * DD + r] = b.w;
    }
    __syncthreads();

    const int wave = threadIdx.x >> 6;
    const int lane = threadIdx.x & 63;
    const int t0 = blockIdx.x * 16 + wave * 4;   // 1024 blocks * 16 tokens

    const float4* xr0 = (const float4*)(x + (size_t)(t0 + 0) * DD);
    const float4* xr1 = (const float4*)(x + (size_t)(t0 + 1) * DD);
    const float4* xr2 = (const float4*)(x + (size_t)(t0 + 2) * DD);
    const float4* xr3 = (const float4*)(x + (size_t)(t0 + 3) * DD);
    const float4* Wt4 = (const float4*)Wt;

    float acc[4][8];
#pragma unroll
    for (int t = 0; t < 4; t++)
#pragma unroll
        for (int e = 0; e < 8; e++) acc[t][e] = 0.f;

#pragma unroll
    for (int j = 0; j < 4; j++) {
        const int idx = j * 64 + lane;           // float4 index in row, 0..255
        float4 wv[8];
#pragma unroll
        for (int e = 0; e < 8; e++) wv[e] = Wt4[e * (DD / 4) + idx];
        float4 xv0 = xr0[idx];
        float4 xv1 = xr1[idx];
        float4 xv2 = xr2[idx];
        float4 xv3 = xr3[idx];
#pragma unroll
        for (int e = 0; e < 8; e++) {
            acc[0][e] += xv0.x * wv[e].x + xv0.y * wv[e].y + xv0.z * wv[e].z + xv0.w * wv[e].w;
            acc[1][e] += xv1.x * wv[e].x + xv1.y * wv[e].y + xv1.z * wv[e].z + xv1.w * wv[e].w;
            acc[2][e] += xv2.x * wv[e].x + xv2.y * wv[e].y + xv2.z * wv[e].z + xv2.w * wv[e].w;
            acc[3][e] += xv3.x * wv[e].x + xv3.y * wv[e].y + xv3.z * wv[e].z + xv3.w * wv[e].w;
        }
    }

    // butterfly reduce across the 64 lanes: afterwards every lane has totals
#pragma unroll
    for (int off = 32; off > 0; off >>= 1) {
#pragma unroll
        for (int t = 0; t < 4; t++)
#pragma unroll
            for (int e = 0; e < 8; e++)
                acc[t][e] += __shfl_xor(acc[t][e], off, 64);
    }

    if (lane == 0) {
#pragma unroll
        for (int t = 0; t < 4; t++) {
            float mx = acc[t][0];
#pragma unroll
            for (int e = 1; e < 8; e++) mx = fmaxf(mx, acc[t][e]);
            float p[8];
            float s = 0.f;
#pragma unroll
            for (int e = 0; e < 8; e++) { p[e] = __expf(acc[t][e] - mx); s += p[e]; }
            const float inv = 1.f / s;
            // top-1 (first occurrence on ties, like argmax)
            int e1 = 0; float g1 = p[0];
#pragma unroll
            for (int e = 1; e < 8; e++) if (p[e] > g1) { g1 = p[e]; e1 = e; }
            // top-2: argmax over gates with top-1 zeroed
            int e2 = -1; float g2 = -1.f;
#pragma unroll
            for (int e = 0; e < 8; e++) if (e != e1 && p[e] > g2) { g2 = p[e]; e2 = e; }
            g1 *= inv; g2 *= inv;
            // faithful to reference: gate_1 updated first, gate_2 uses updated gate_1
            const float g1n = g1 / (g1 + g2 + EPSV);
            const float g2n = g2 / (g1n + g2 + EPSV);
            if (!(g2n > THRESH)) e2 = -1;   // threshold folds into invalid expert
            rec[t0 + t] = make_float4(__int_as_float(e1), g1n, __int_as_float(e2), g2n);
        }
    }
}

// ---------------------------------------------------------------------------
// Kernel 2: per-batch sequential scan over tokens (exclusive cumsum per gate)
// via ballot/popcount, 64 tokens per step. One wave per batch; all 32 chunk
// records held in registers (occupancy irrelevant: 8 waves total).
// Output record: {int o1_or_-1, float g1, int o2_or_-1, float g2} where
// o = expert*CAP + position (slab-flat offset in [0, 2560)).
// ---------------------------------------------------------------------------
__global__ __launch_bounds__(64) void scan_kernel(const float4* __restrict__ rin,
                                                  float4* __restrict__ rout) {
    const int b = blockIdx.x;
    const int lane = threadIdx.x;
    const int base = b * NN;
    const unsigned long long lt = (1ull << lane) - 1ull;   // lanes below me

    float4 recs[32];
#pragma unroll
    for (int i = 0; i < 32; i++) recs[i] = rin[base + i * 64 + lane];

    int pos1[32];
    int cnt[8] = {0, 0, 0, 0, 0, 0, 0, 0};

    // pass 1: positions in expert for top-1 choices (mask_1 is always 1 pre-capacity)
#pragma unroll
    for (int i = 0; i < 32; i++) {
        const int e1 = __float_as_int(recs[i].x);
        int p = 0;
#pragma unroll
        for (int g = 0; g < 8; g++) {
            const bool is = (e1 == g);
            const unsigned long long m = __ballot(is);
            if (is) p = cnt[g] + __popcll(m & lt);
            cnt[g] += __popcll(m);
        }
        pos1[i] = p;
    }

    // mask_1_count (post-capacity) = min(count, CAP) -> base offset for expert-2
#pragma unroll
    for (int g = 0; g < 8; g++) cnt[g] = min(cnt[g], CAP);

    // pass 2: positions for thresholded top-2 choices, offset by mask_1_count
#pragma unroll
    for (int i = 0; i < 32; i++) {
        const int e2 = __float_as_int(recs[i].z);
        int p2 = CAP;   // sentinel: invalid unless set below
#pragma unroll
        for (int g = 0; g < 8; g++) {
            const bool is = (e2 == g);
            const unsigned long long m = __ballot(is);
            if (is) p2 = cnt[g] + __popcll(m & lt);
            cnt[g] += __popcll(m);
        }
        const int e1 = __float_as_int(recs[i].x);
        const int o1 = (pos1[i] < CAP) ? (e1 * CAP + pos1[i]) : -1;
        const int o2 = (e2 >= 0 && p2 < CAP) ? (e2 * CAP + p2) : -1;
        rout[base + i * 64 + lane] =
            make_float4(__int_as_float(o1), recs[i].y, __int_as_float(o2), recs[i].w);
    }
}

// ---------------------------------------------------------------------------
// Kernel 3 (NEW): fused zero-fill + scatter. Writes the ENTIRE output exactly
// once, fully coalesced (16 B/lane), injecting each token's <=2 nonzeros
// inline. Replaces hipMemsetAsync (which was zeroing 4x the output size --
// out_size is in BYTES -- 671 MB written per iteration per rocprof) plus the
// read-modify-write scatter kernel. Write floor: 160 MiB / ~6.5 TB/s ~= 26 us.
//
// One wave per token slab (2560 floats = 640 float4 -> 10 float4 per lane),
// 4 slabs per 256-thread block -> 4096 blocks.
// o1/o2 are flat offsets in [0, 2560) or -1; -1 never matches a component
// index so no validity branch is needed.
// ---------------------------------------------------------------------------
__global__ __launch_bounds__(256) void write_kernel(const float4* __restrict__ rec,
                                                    float4* __restrict__ out) {
    const int wave = threadIdx.x >> 6;
    const int lane = threadIdx.x & 63;
    const int t = blockIdx.x * 4 + wave;

    const float4 r = rec[t];                 // broadcast load (same addr per wave)
    const int o1 = __float_as_int(r.x);
    const int o2 = __float_as_int(r.z);
    const float g1 = r.y;
    const float g2 = r.w;

    float4* slab = out + (size_t)t * (GG * CAP / 4);   // 640 float4 per token
#pragma unroll
    for (int i = 0; i < 10; i++) {
        const int f4 = i * 64 + lane;        // float4 index within slab
        const int e0 = f4 * 4;               // flat element index of component .x
        float4 v;
        v.x = (o1 == e0    ) ? g1 : ((o2 == e0    ) ? g2 : 0.f);
        v.y = (o1 == e0 + 1) ? g1 : ((o2 == e0 + 1) ? g2 : 0.f);
        v.z = (o1 == e0 + 2) ? g1 : ((o2 == e0 + 2) ? g2 : 0.f);
        v.w = (o1 == e0 + 3) ? g1 : ((o2 == e0 + 3) ? g2 : 0.f);
        slab[f4] = v;
    }
}

extern "C" void kernel_launch(void* const* d_in, const int* in_sizes, int n_in,
                              void* d_out, int out_size, void* d_ws, size_t ws_size,
                              hipStream_t stream) {
    const float* x = (const float*)d_in[0];          // [8, 2048, 1024] fp32
    const float* W = (const float*)d_in[1];          // [1024, 8] fp32
    float4* out = (float4*)d_out;                    // [8, 2048, 8, 320] fp32

    float4* rec1 = (float4*)d_ws;                    // 16384 * 16 B
    float4* rec2 = rec1 + NTOK;                      // 16384 * 16 B

    gate_kernel<<<NTOK / 16, 256, 0, stream>>>(x, W, rec1);
    scan_kernel<<<BB, 64, 0, stream>>>(rec1, rec2);
    write_kernel<<<NTOK / 4, 256, 0, stream>>>(rec2, out);
}